// Round 5
// baseline (551.937 us; speedup 1.0000x reference)
//
#include <hip/hip_runtime.h>
#include <math.h>

#define BATCH   65536
#define DIM     64
#define HID     128
#define SPLIT   32
#define NBINS   8
#define PDIM    25          // 3*NBINS+1
#define NLAYERS 6
#define R_MIN   (-5.0f)
#define R_MAX   (5.0f)
#define MIN_BIN   1.0e-4f
#define MIN_SLOPE 1.0e-4f
#define SOFF      0.54116666f   // log(exp(1-MIN_SLOPE)-1)

#define ROWSW 32      // rows per wave
#define WAVES 2
#define MBLK  64      // rows per block
#define NT    128

#define N_W1  (HID*SPLIT)      // 4096
#define N_W2  (HID*HID)        // 16384
#define N_W4P (32*32*HID)      // 131072 (padded: 8 tb x 8 pq x 4 kt chunks of 512)
#define N_W4  (SPLIT*PDIM*HID) // 102400

typedef __attribute__((ext_vector_type(8))) short bf16x8;
typedef __attribute__((ext_vector_type(4))) float f32x4;

__device__ __forceinline__ short f2bf(float f) {
    unsigned u = __builtin_bit_cast(unsigned, f);
    unsigned r = u + 0x7FFFu + ((u >> 16) & 1u);   // RNE
    return (short)(r >> 16);
}

__device__ __forceinline__ unsigned pk2(float a, float b) {   // 2xf32 -> packed bf16 (RNE)
    unsigned r;
    asm("v_cvt_pk_bf16_f32 %0, %1, %2" : "=v"(r) : "v"(a), "v"(b));
    return r;
}

// LDS act layout: [group g = n>>2][row r][n&3] shorts, group stride 128 shorts.
// B-fragment (lane: row = l&15 (+16*rh), k = (l>>4)*8+e): two b64 reads 256B apart.
__device__ __forceinline__ bf16x8 ldfrag(const short* base) {
    short4 lo = *reinterpret_cast<const short4*>(base);
    short4 hi = *reinterpret_cast<const short4*>(base + 128);
    bf16x8 a;
    a[0]=lo.x; a[1]=lo.y; a[2]=lo.z; a[3]=lo.w;
    a[4]=hi.x; a[5]=hi.y; a[6]=hi.z; a[7]=hi.w;
    return a;
}

// ---- weight conversion prologue ----
// W1/W2/W3: 16(n) x 32(k) fragment chunks (lane l: n-row = l&15, k = (l>>4)*8+e).
// W4: chunks (tb, pq, kt): A-row r = 4*t_sub + p_sub, so lane l supplies
//     t = tb*4 + ((l&15)>>2), p = pq*4 + (l&3) -> D rows land per-lane with
//     the lane's OWN t (t = tb*4 + lg) and params pq*4+j. Pad p>=25 with 0.
// b4q: bias padded to 32 per t.
__global__ void cvt_weights(const float* __restrict__ W1, const float* __restrict__ W2,
                            const float* __restrict__ W3, const float* __restrict__ W4,
                            const float* __restrict__ b4,
                            short* __restrict__ o1, short* __restrict__ o2,
                            short* __restrict__ o3, short* __restrict__ o4,
                            float* __restrict__ b4q) {
    const int stride = gridDim.x * blockDim.x;
    const int i0 = blockIdx.x * blockDim.x + threadIdx.x;
    for (int i = i0; i < NLAYERS*N_W1; i += stride) {
        const int L = i >> 12, rem = i & 4095;
        const int nt = rem >> 9, q = rem & 511;
        const int l = q >> 3, e = q & 7;
        o1[i] = f2bf(W1[L*N_W1 + (nt*16 + (l&15))*SPLIT + (l>>4)*8 + e]);
    }
    for (int i = i0; i < NLAYERS*N_W2; i += stride) {
        const int L = i >> 14, rem = i & 16383;
        const int c = rem >> 9, q = rem & 511;
        const int nt = c >> 2, kt = c & 3;
        const int l = q >> 3, e = q & 7;
        const int src = L*N_W2 + (nt*16 + (l&15))*HID + kt*32 + (l>>4)*8 + e;
        o2[i] = f2bf(W2[src]);
        o3[i] = f2bf(W3[src]);
    }
    for (int i = i0; i < NLAYERS*N_W4P; i += stride) {
        const int L = i >> 17, rem = i & (N_W4P - 1);
        const int c = rem >> 9, q = rem & 511;
        const int tb = c >> 5, pq = (c >> 2) & 7, kt = c & 3;
        const int l = q >> 3, e = q & 7;
        const int t = tb*4 + ((l & 15) >> 2);
        const int p = pq*4 + (l & 3);
        o4[i] = (p < PDIM)
              ? f2bf(W4[(size_t)L*N_W4 + (size_t)(t*PDIM + p)*HID + kt*32 + (l>>4)*8 + e])
              : (short)0;
    }
    for (int i = i0; i < NLAYERS*SPLIT*32; i += stride) {
        const int L = i >> 10, rem = i & 1023;
        const int t = rem >> 5, p = rem & 31;
        b4q[i] = (p < PDIM) ? b4[L*SPLIT*PDIM + t*PDIM + p] : 0.0f;
    }
}

// One coupling layer. Each WAVE owns 32 rows end-to-end (no __syncthreads).
// MFMA orientation: D = W_frag(A) x act_frag(B) -> D[n][row]; lane (lr,lg)
// holds n = base + lg*4+j for row lr(+16). Activations live in LDS as bf16.
__global__ __launch_bounds__(NT, 3) void flow_layer(
    const float* xin, float* yout, float* logdet, const int first,
    const short* __restrict__ bW1, const float* __restrict__ b1,
    const short* __restrict__ bW2, const float* __restrict__ b2,
    const short* __restrict__ bW3, const float* __restrict__ b3,
    const short* __restrict__ bW4, const float* __restrict__ b4q,
    const int* __restrict__ mi, const int* __restrict__ ti)
{
    __shared__ short act[WAVES][32 * 128];        // 32 groups x 32 rows x 4 shorts
    __shared__ float xts[WAVES][ROWSW][33];       // spline inputs (f32)

    const int tid = threadIdx.x;
    const int wv  = tid >> 6;    // wave id
    const int l   = tid & 63;    // lane
    const int lr  = l & 15;      // row-in-half / col-in-tile
    const int lg  = l >> 4;      // 0..3
    const int rbase = blockIdx.x * MBLK + wv * ROWSW;

    short* const actw = &act[wv][0];

    // ---- gather: xm -> act groups 0..7 (bf16), xt -> xts (f32) ----
    {
        const int kcol = l & 31;
        const int mc = mi[kcol], tc = ti[kcol];
        const int r0 = l >> 5;                    // 0 or 1
        #pragma unroll
        for (int it = 0; it < 16; ++it) {
            const int r = r0 + it * 2;
            const float* row = xin + (size_t)(rbase + r) * DIM;
            const float mv = row[mc];
            actw[(kcol >> 2)*128 + r*4 + (kcol & 3)] = f2bf(mv);
            xts[wv][r][kcol] = row[tc];
            if (first) yout[(size_t)(rbase + r) * DIM + mc] = mv;  // copy-through (L0)
        }
    }

    // ================= h1 = relu(W1 @ xm^T + b1)  [K=32] =================
    {
        bf16x8 afr[2];
        #pragma unroll
        for (int rh = 0; rh < 2; ++rh)
            afr[rh] = ldfrag(&actw[(2*lg)*128 + (lr + rh*16)*4]);
        f32x4 c[8][2];
        #pragma unroll
        for (int nt = 0; nt < 8; ++nt) {
            const float4 bv = *reinterpret_cast<const float4*>(b1 + nt*16 + lg*4);
            c[nt][0] = (f32x4){bv.x, bv.y, bv.z, bv.w};
            c[nt][1] = c[nt][0];
        }
        #pragma unroll
        for (int nt = 0; nt < 8; ++nt) {
            const bf16x8 wfr = *reinterpret_cast<const bf16x8*>(bW1 + (size_t)nt*512 + l*8);
            #pragma unroll
            for (int rh = 0; rh < 2; ++rh)
                c[nt][rh] = __builtin_amdgcn_mfma_f32_16x16x32_bf16(wfr, afr[rh], c[nt][rh], 0, 0, 0);
        }
        #pragma unroll
        for (int nt = 0; nt < 8; ++nt)
            #pragma unroll
            for (int rh = 0; rh < 2; ++rh) {
                const unsigned u0 = pk2(fmaxf(c[nt][rh][0], 0.0f), fmaxf(c[nt][rh][1], 0.0f));
                const unsigned u1 = pk2(fmaxf(c[nt][rh][2], 0.0f), fmaxf(c[nt][rh][3], 0.0f));
                *reinterpret_cast<uint2*>(&actw[(nt*4 + lg)*128 + (lr + rh*16)*4]) = (uint2){u0, u1};
            }
    }

    // ================= h2 / h3  [K=128] =================
    #pragma unroll 1
    for (int ph = 0; ph < 2; ++ph) {
        const short* Wp = ph ? bW3 : bW2;
        const float* bp = ph ? b3  : b2;
        bf16x8 afr[4][2];
        #pragma unroll
        for (int kt = 0; kt < 4; ++kt)
            #pragma unroll
            for (int rh = 0; rh < 2; ++rh)
                afr[kt][rh] = ldfrag(&actw[(kt*8 + 2*lg)*128 + (lr + rh*16)*4]);
        f32x4 c[8][2];
        #pragma unroll
        for (int nt = 0; nt < 8; ++nt) {
            const float4 bv = *reinterpret_cast<const float4*>(bp + nt*16 + lg*4);
            c[nt][0] = (f32x4){bv.x, bv.y, bv.z, bv.w};
            c[nt][1] = c[nt][0];
        }
        #pragma unroll
        for (int kt = 0; kt < 4; ++kt)
            #pragma unroll
            for (int nt = 0; nt < 8; ++nt) {
                const bf16x8 wfr = *reinterpret_cast<const bf16x8*>(Wp + (size_t)(nt*4 + kt)*512 + l*8);
                #pragma unroll
                for (int rh = 0; rh < 2; ++rh)
                    c[nt][rh] = __builtin_amdgcn_mfma_f32_16x16x32_bf16(wfr, afr[kt][rh], c[nt][rh], 0, 0, 0);
            }
        #pragma unroll
        for (int nt = 0; nt < 8; ++nt)
            #pragma unroll
            for (int rh = 0; rh < 2; ++rh) {
                const unsigned u0 = pk2(fmaxf(c[nt][rh][0], 0.0f), fmaxf(c[nt][rh][1], 0.0f));
                const unsigned u1 = pk2(fmaxf(c[nt][rh][2], 0.0f), fmaxf(c[nt][rh][3], 0.0f));
                *reinterpret_cast<uint2*>(&actw[(nt*4 + lg)*128 + (lr + rh*16)*4]) = (uint2){u0, u1};
            }
    }

    // ================= W4 params + RQS spline =================
    // B-fragments (h3 acts) held in registers for the whole tb loop.
    bf16x8 afr[4][2];
    #pragma unroll
    for (int kt = 0; kt < 4; ++kt)
        #pragma unroll
        for (int rh = 0; rh < 2; ++rh)
            afr[kt][rh] = ldfrag(&actw[(kt*8 + 2*lg)*128 + (lr + rh*16)*4]);

    float ld0 = 0.0f, ld1 = 0.0f;
    #pragma unroll 1
    for (int tb = 0; tb < 8; ++tb) {
        const int t = tb*4 + lg;           // this lane's t-dim
        f32x4 c[8][2];
        #pragma unroll
        for (int pq = 0; pq < 8; ++pq) {
            const float4 bv = *reinterpret_cast<const float4*>(b4q + t*32 + pq*4);
            c[pq][0] = (f32x4){bv.x, bv.y, bv.z, bv.w};
            c[pq][1] = c[pq][0];
        }
        #pragma unroll
        for (int kt = 0; kt < 4; ++kt)
            #pragma unroll
            for (int pq = 0; pq < 8; ++pq) {
                const bf16x8 wfr = *reinterpret_cast<const bf16x8*>(
                    bW4 + (size_t)((tb*8 + pq)*4 + kt)*512 + l*8);
                #pragma unroll
                for (int rh = 0; rh < 2; ++rh)
                    c[pq][rh] = __builtin_amdgcn_mfma_f32_16x16x32_bf16(wfr, afr[kt][rh], c[pq][rh], 0, 0, 0);
            }

        const int ticol = ti[t];
        #pragma unroll
        for (int rh = 0; rh < 2; ++rh) {
            float p[32];
            #pragma unroll
            for (int pq = 0; pq < 8; ++pq)
                #pragma unroll
                for (int j = 0; j < 4; ++j) p[pq*4 + j] = c[pq][rh][j];

            const int r = lr + rh*16;

            float sl[NBINS + 1];
            #pragma unroll
            for (int i = 0; i < NBINS + 1; ++i) {
                const float z = p[2*NBINS + i] + SOFF;
                const float sp = (z > 15.0f) ? z : __logf(1.0f + __expf(z));
                sl[i] = sp + MIN_SLOPE;
            }
            float wd[NBINS];
            {
                float mx = p[0];
                #pragma unroll
                for (int i = 1; i < NBINS; ++i) mx = fmaxf(mx, p[i]);
                float sum = 0.0f;
                #pragma unroll
                for (int i = 0; i < NBINS; ++i) { wd[i] = __expf(p[i] - mx); sum += wd[i]; }
                const float sc = __fdividef((R_MAX - R_MIN) - NBINS * MIN_BIN, sum);
                #pragma unroll
                for (int i = 0; i < NBINS; ++i) wd[i] = wd[i] * sc + MIN_BIN;
            }
            float hg[NBINS];
            {
                float mx = p[NBINS];
                #pragma unroll
                for (int i = 1; i < NBINS; ++i) mx = fmaxf(mx, p[NBINS + i]);
                float sum = 0.0f;
                #pragma unroll
                for (int i = 0; i < NBINS; ++i) { hg[i] = __expf(p[NBINS + i] - mx); sum += hg[i]; }
                const float sc = __fdividef((R_MAX - R_MIN) - NBINS * MIN_BIN, sum);
                #pragma unroll
                for (int i = 0; i < NBINS; ++i) hg[i] = hg[i] * sc + MIN_BIN;
            }

            const float x = xts[wv][r][t];

            int b = 0;
            {
                float cx = R_MIN;
                #pragma unroll
                for (int i = 1; i < NBINS; ++i) { cx += wd[i-1]; b += (cx <= x) ? 1 : 0; }
            }
            float x_k = R_MIN, y_k = R_MIN, wsel = wd[0], hsel = hg[0], d_k = sl[0], d_k1 = sl[1];
            {
                float cx = R_MIN, cy = R_MIN;
                #pragma unroll
                for (int i = 0; i < NBINS; ++i) {
                    if (i == b) { x_k = cx; y_k = cy; wsel = wd[i]; hsel = hg[i];
                                  d_k = sl[i]; d_k1 = sl[i+1]; }
                    cx += wd[i]; cy += hg[i];
                }
            }

            const float invw = __fdividef(1.0f, wsel);
            float xi = (x - x_k) * invw;
            xi = fminf(fmaxf(xi, 0.0f), 1.0f);
            const float s    = hsel * invw;
            const float xi1m = 1.0f - xi;
            const float q    = xi * xi1m;
            const float num  = s * xi * xi + d_k * q;
            const float den  = s + (d_k1 + d_k - 2.0f * s) * q;
            const float invden = __fdividef(1.0f, den);
            const float y_sp = y_k + hsel * num * invden;
            const float deriv = s * s * (d_k1 * xi * xi + 2.0f * s * q + d_k * xi1m * xi1m)
                                * invden * invden;

            const bool below = x < R_MIN;
            const bool above = x > R_MAX;
            const float yv = below ? ((x - R_MIN) * sl[0]     + R_MIN)
                           : (above ? ((x - R_MAX) * sl[NBINS] + R_MAX) : y_sp);
            const float dv = below ? sl[0] : (above ? sl[NBINS] : deriv);
            if (rh == 0) ld0 += __logf(dv); else ld1 += __logf(dv);

            yout[(size_t)(rbase + r) * DIM + ticol] = yv;
        }
    }

    // per-row logdet: reduce over the 4 lane-groups (fixed order)
    ld0 += __shfl_xor(ld0, 16, 64);
    ld0 += __shfl_xor(ld0, 32, 64);
    ld1 += __shfl_xor(ld1, 16, 64);
    ld1 += __shfl_xor(ld1, 32, 64);
    if (l < 16) {
        const int row0 = rbase + lr;
        if (first) { logdet[row0] = ld0; logdet[row0 + 16] = ld1; }
        else       { logdet[row0] += ld0; logdet[row0 + 16] += ld1; }
    }
}

extern "C" void kernel_launch(void* const* d_in, const int* in_sizes, int n_in,
                              void* d_out, int out_size, void* d_ws, size_t ws_size,
                              hipStream_t stream) {
    const float* x  = (const float*)d_in[0];
    const float* W1 = (const float*)d_in[1];
    const float* b1 = (const float*)d_in[2];
    const float* W2 = (const float*)d_in[3];
    const float* b2 = (const float*)d_in[4];
    const float* W3 = (const float*)d_in[5];
    const float* b3 = (const float*)d_in[6];
    const float* W4 = (const float*)d_in[7];
    const float* b4 = (const float*)d_in[8];
    const int*   mi = (const int*)d_in[9];
    const int*   ti = (const int*)d_in[10];

    float* y      = (float*)d_out;
    float* logdet = y + (size_t)BATCH * DIM;

    short* bW1 = (short*)d_ws;
    short* bW2 = bW1 + NLAYERS * N_W1;
    short* bW3 = bW2 + NLAYERS * N_W2;
    short* bW4 = bW3 + NLAYERS * N_W2;
    float* b4q = (float*)(bW4 + (size_t)NLAYERS * N_W4P);

    cvt_weights<<<512, 256, 0, stream>>>(W1, W2, W3, W4, b4, bW1, bW2, bW3, bW4, b4q);

    dim3 grid(BATCH / MBLK), block(NT);
    for (int L = 0; L < NLAYERS; ++L) {
        flow_layer<<<grid, block, 0, stream>>>(
            (L == 0) ? x : y, y, logdet, (L == 0) ? 1 : 0,
            bW1 + (size_t)L * N_W1, b1 + L * HID,
            bW2 + (size_t)L * N_W2, b2 + L * HID,
            bW3 + (size_t)L * N_W2, b3 + L * HID,
            bW4 + (size_t)L * N_W4P, b4q + (size_t)L * SPLIT * 32,
            mi + L * SPLIT, ti + L * SPLIT);
    }
}

// Round 6
// 362.632 us; speedup vs baseline: 1.5220x; 1.5220x over previous
//
#include <hip/hip_runtime.h>
#include <math.h>

#define BATCH   65536
#define DIM     64
#define HID     128
#define SPLIT   32
#define NBINS   8
#define PDIM    25          // 3*NBINS+1
#define NLAYERS 6
#define R_MIN   (-5.0f)
#define R_MAX   (5.0f)
#define MIN_BIN   1.0e-4f
#define MIN_SLOPE 1.0e-4f
#define SOFF      0.54116666f   // log(exp(1-MIN_SLOPE)-1)

#define ROWSW 16      // rows per wave
#define WAVES 4
#define MBLK  64      // rows per block
#define NT    256

#define N_W1  (HID*SPLIT)      // 4096
#define N_W2  (HID*HID)        // 16384
#define N_W4P (32*32*HID)      // 131072 (8 tb x 8 pq x 4 kt chunks of 512)
#define N_W4  (SPLIT*PDIM*HID) // 102400

typedef __attribute__((ext_vector_type(8))) short bf16x8;
typedef __attribute__((ext_vector_type(4))) float f32x4;

__device__ __forceinline__ short f2bf(float f) {
    unsigned u = __builtin_bit_cast(unsigned, f);
    unsigned r = u + 0x7FFFu + ((u >> 16) & 1u);   // RNE
    return (short)(r >> 16);
}

__device__ __forceinline__ unsigned pk2(float a, float b) {   // 2xf32 -> packed bf16 (RNE)
    unsigned r;
    asm("v_cvt_pk_bf16_f32 %0, %1, %2" : "=v"(r) : "v"(a), "v"(b));
    return r;
}

// LDS act layout: [group g = k>>2][row r][k&3] shorts, group stride 64 shorts.
// B-fragment (lane: col/row = l&15, k = (l>>4)*8+e): two b64 reads 128B apart.
__device__ __forceinline__ bf16x8 ldfrag(const short* base) {
    short4 lo = *reinterpret_cast<const short4*>(base);
    short4 hi = *reinterpret_cast<const short4*>(base + 64);
    bf16x8 a;
    a[0]=lo.x; a[1]=lo.y; a[2]=lo.z; a[3]=lo.w;
    a[4]=hi.x; a[5]=hi.y; a[6]=hi.z; a[7]=hi.w;
    return a;
}

// ---- weight conversion prologue ----
// W1/W2/W3: 16(n) x 32(k) A-fragment chunks (lane l: n-row = l&15, k = (l>>4)*8+e).
// W4: chunks (tb, pq, kt): A-row = 4*t_sub + p_sub -> lane l supplies
//     t = tb*4 + ((l&15)>>2), p = pq*4 + (l&3); D regs then hold the lane's
//     OWN (row, t) spline params. Pad p>=25 with 0. b4q: bias padded to 32/t.
__global__ void cvt_weights(const float* __restrict__ W1, const float* __restrict__ W2,
                            const float* __restrict__ W3, const float* __restrict__ W4,
                            const float* __restrict__ b4,
                            short* __restrict__ o1, short* __restrict__ o2,
                            short* __restrict__ o3, short* __restrict__ o4,
                            float* __restrict__ b4q) {
    const int stride = gridDim.x * blockDim.x;
    const int i0 = blockIdx.x * blockDim.x + threadIdx.x;
    for (int i = i0; i < NLAYERS*N_W1; i += stride) {
        const int L = i >> 12, rem = i & 4095;
        const int nt = rem >> 9, q = rem & 511;
        const int l = q >> 3, e = q & 7;
        o1[i] = f2bf(W1[L*N_W1 + (nt*16 + (l&15))*SPLIT + (l>>4)*8 + e]);
    }
    for (int i = i0; i < NLAYERS*N_W2; i += stride) {
        const int L = i >> 14, rem = i & 16383;
        const int c = rem >> 9, q = rem & 511;
        const int nt = c >> 2, kt = c & 3;
        const int l = q >> 3, e = q & 7;
        const int src = L*N_W2 + (nt*16 + (l&15))*HID + kt*32 + (l>>4)*8 + e;
        o2[i] = f2bf(W2[src]);
        o3[i] = f2bf(W3[src]);
    }
    for (int i = i0; i < NLAYERS*N_W4P; i += stride) {
        const int L = i >> 17, rem = i & (N_W4P - 1);
        const int c = rem >> 9, q = rem & 511;
        const int tb = c >> 5, pq = (c >> 2) & 7, kt = c & 3;
        const int l = q >> 3, e = q & 7;
        const int t = tb*4 + ((l & 15) >> 2);
        const int p = pq*4 + (l & 3);
        o4[i] = (p < PDIM)
              ? f2bf(W4[(size_t)L*N_W4 + (size_t)(t*PDIM + p)*HID + kt*32 + (l>>4)*8 + e])
              : (short)0;
    }
    for (int i = i0; i < NLAYERS*SPLIT*32; i += stride) {
        const int L = i >> 10, rem = i & 1023;
        const int t = rem >> 5, p = rem & 31;
        b4q[i] = (p < PDIM) ? b4[L*SPLIT*PDIM + t*PDIM + p] : 0.0f;
    }
}

// One coupling layer. Each WAVE owns 16 rows end-to-end (no __syncthreads).
// MFMA: D = W_frag(A) x act_frag(B) -> D[n][row]; lane (lr,lg) holds
// n = base + lg*4+j for row lr. Acts live in LDS as bf16 fragment groups.
__global__ __launch_bounds__(NT, 4) void flow_layer(
    const float* xin, float* yout, float* logdet, const int first,
    const short* __restrict__ bW1, const float* __restrict__ b1,
    const short* __restrict__ bW2, const float* __restrict__ b2,
    const short* __restrict__ bW3, const float* __restrict__ b3,
    const short* __restrict__ bW4, const float* __restrict__ b4q,
    const int* __restrict__ mi, const int* __restrict__ ti)
{
    __shared__ short act[WAVES][32 * 64];         // 32 groups x 16 rows x 4 shorts
    __shared__ float xts[WAVES][ROWSW][33];       // spline inputs (f32)

    const int tid = threadIdx.x;
    const int wv  = tid >> 6;    // wave id
    const int l   = tid & 63;    // lane
    const int lr  = l & 15;      // row / col-in-tile
    const int lg  = l >> 4;      // 0..3
    const int rbase = blockIdx.x * MBLK + wv * ROWSW;

    short* const actw = &act[wv][0];

    // ---- gather: xm -> act groups 0..7 (bf16), xt -> xts (f32) ----
    {
        const int kcol = l & 31;
        const int mc = mi[kcol], tc = ti[kcol];
        const int r0 = l >> 5;                    // 0 or 1
        #pragma unroll
        for (int it = 0; it < 8; ++it) {
            const int r = r0 + it * 2;
            const float* row = xin + (size_t)(rbase + r) * DIM;
            const float mv = row[mc];
            actw[(kcol >> 2)*64 + r*4 + (kcol & 3)] = f2bf(mv);
            xts[wv][r][kcol] = row[tc];
            if (first) yout[(size_t)(rbase + r) * DIM + mc] = mv;  // copy-through (L0)
        }
    }

    // ================= h1 = relu(W1 @ xm^T + b1)  [K=32] =================
    {
        const bf16x8 afr = ldfrag(&actw[(2*lg)*64 + lr*4]);
        f32x4 c[8];
        #pragma unroll
        for (int nt = 0; nt < 8; ++nt) {
            const float4 bv = *reinterpret_cast<const float4*>(b1 + nt*16 + lg*4);
            c[nt] = (f32x4){bv.x, bv.y, bv.z, bv.w};
        }
        #pragma unroll
        for (int nt = 0; nt < 8; ++nt) {
            const bf16x8 wfr = *reinterpret_cast<const bf16x8*>(bW1 + (size_t)nt*512 + l*8);
            c[nt] = __builtin_amdgcn_mfma_f32_16x16x32_bf16(wfr, afr, c[nt], 0, 0, 0);
        }
        #pragma unroll
        for (int nt = 0; nt < 8; ++nt) {
            const unsigned u0 = pk2(fmaxf(c[nt][0], 0.0f), fmaxf(c[nt][1], 0.0f));
            const unsigned u1 = pk2(fmaxf(c[nt][2], 0.0f), fmaxf(c[nt][3], 0.0f));
            *reinterpret_cast<uint2*>(&actw[(nt*4 + lg)*64 + lr*4]) = (uint2){u0, u1};
        }
    }

    // ================= h2 / h3  [K=128] =================
    #pragma unroll 1
    for (int ph = 0; ph < 2; ++ph) {
        const short* Wp = ph ? bW3 : bW2;
        const float* bp = ph ? b3  : b2;
        bf16x8 afr[4];
        #pragma unroll
        for (int kt = 0; kt < 4; ++kt)
            afr[kt] = ldfrag(&actw[(kt*8 + 2*lg)*64 + lr*4]);
        f32x4 c[8];
        #pragma unroll
        for (int nt = 0; nt < 8; ++nt) {
            const float4 bv = *reinterpret_cast<const float4*>(bp + nt*16 + lg*4);
            c[nt] = (f32x4){bv.x, bv.y, bv.z, bv.w};
        }
        #pragma unroll
        for (int kt = 0; kt < 4; ++kt)
            #pragma unroll
            for (int nt = 0; nt < 8; ++nt) {
                const bf16x8 wfr = *reinterpret_cast<const bf16x8*>(Wp + (size_t)(nt*4 + kt)*512 + l*8);
                c[nt] = __builtin_amdgcn_mfma_f32_16x16x32_bf16(wfr, afr[kt], c[nt], 0, 0, 0);
            }
        #pragma unroll
        for (int nt = 0; nt < 8; ++nt) {
            const unsigned u0 = pk2(fmaxf(c[nt][0], 0.0f), fmaxf(c[nt][1], 0.0f));
            const unsigned u1 = pk2(fmaxf(c[nt][2], 0.0f), fmaxf(c[nt][3], 0.0f));
            *reinterpret_cast<uint2*>(&actw[(nt*4 + lg)*64 + lr*4]) = (uint2){u0, u1};
        }
    }

    // ================= W4 params + RQS spline =================
    bf16x8 afr[4];
    #pragma unroll
    for (int kt = 0; kt < 4; ++kt)
        afr[kt] = ldfrag(&actw[(kt*8 + 2*lg)*64 + lr*4]);

    float ldacc = 0.0f;
    #pragma unroll 1
    for (int tb = 0; tb < 8; ++tb) {
        const int t = tb*4 + lg;           // this lane's t-dim
        f32x4 c[8];
        #pragma unroll
        for (int pq = 0; pq < 8; ++pq) {
            const float4 bv = *reinterpret_cast<const float4*>(b4q + t*32 + pq*4);
            c[pq] = (f32x4){bv.x, bv.y, bv.z, bv.w};
        }
        #pragma unroll
        for (int kt = 0; kt < 4; ++kt)
            #pragma unroll
            for (int pq = 0; pq < 8; ++pq) {
                const bf16x8 wfr = *reinterpret_cast<const bf16x8*>(
                    bW4 + (size_t)((tb*8 + pq)*4 + kt)*512 + l*8);
                c[pq] = __builtin_amdgcn_mfma_f32_16x16x32_bf16(wfr, afr[kt], c[pq], 0, 0, 0);
            }

        // lane now holds the full 32 params of (row = lr, t)
        float p[32];
        #pragma unroll
        for (int pq = 0; pq < 8; ++pq)
            #pragma unroll
            for (int j = 0; j < 4; ++j) p[pq*4 + j] = c[pq][j];

        float sl[NBINS + 1];
        #pragma unroll
        for (int i = 0; i < NBINS + 1; ++i) {
            const float z = p[2*NBINS + i] + SOFF;
            const float sp = (z > 15.0f) ? z : __logf(1.0f + __expf(z));
            sl[i] = sp + MIN_SLOPE;
        }
        float wd[NBINS];
        {
            float mx = p[0];
            #pragma unroll
            for (int i = 1; i < NBINS; ++i) mx = fmaxf(mx, p[i]);
            float sum = 0.0f;
            #pragma unroll
            for (int i = 0; i < NBINS; ++i) { wd[i] = __expf(p[i] - mx); sum += wd[i]; }
            const float sc = __fdividef((R_MAX - R_MIN) - NBINS * MIN_BIN, sum);
            #pragma unroll
            for (int i = 0; i < NBINS; ++i) wd[i] = wd[i] * sc + MIN_BIN;
        }
        float hg[NBINS];
        {
            float mx = p[NBINS];
            #pragma unroll
            for (int i = 1; i < NBINS; ++i) mx = fmaxf(mx, p[NBINS + i]);
            float sum = 0.0f;
            #pragma unroll
            for (int i = 0; i < NBINS; ++i) { hg[i] = __expf(p[NBINS + i] - mx); sum += hg[i]; }
            const float sc = __fdividef((R_MAX - R_MIN) - NBINS * MIN_BIN, sum);
            #pragma unroll
            for (int i = 0; i < NBINS; ++i) hg[i] = hg[i] * sc + MIN_BIN;
        }

        const float x = xts[wv][lr][t];

        int b = 0;
        {
            float cx = R_MIN;
            #pragma unroll
            for (int i = 1; i < NBINS; ++i) { cx += wd[i-1]; b += (cx <= x) ? 1 : 0; }
        }
        float x_k = R_MIN, y_k = R_MIN, wsel = wd[0], hsel = hg[0], d_k = sl[0], d_k1 = sl[1];
        {
            float cx = R_MIN, cy = R_MIN;
            #pragma unroll
            for (int i = 0; i < NBINS; ++i) {
                if (i == b) { x_k = cx; y_k = cy; wsel = wd[i]; hsel = hg[i];
                              d_k = sl[i]; d_k1 = sl[i+1]; }
                cx += wd[i]; cy += hg[i];
            }
        }

        const float invw = __fdividef(1.0f, wsel);
        float xi = (x - x_k) * invw;
        xi = fminf(fmaxf(xi, 0.0f), 1.0f);
        const float s    = hsel * invw;
        const float xi1m = 1.0f - xi;
        const float q    = xi * xi1m;
        const float num  = s * xi * xi + d_k * q;
        const float den  = s + (d_k1 + d_k - 2.0f * s) * q;
        const float invden = __fdividef(1.0f, den);
        const float y_sp = y_k + hsel * num * invden;
        const float deriv = s * s * (d_k1 * xi * xi + 2.0f * s * q + d_k * xi1m * xi1m)
                            * invden * invden;

        const bool below = x < R_MIN;
        const bool above = x > R_MAX;
        const float yv = below ? ((x - R_MIN) * sl[0]     + R_MIN)
                       : (above ? ((x - R_MAX) * sl[NBINS] + R_MAX) : y_sp);
        const float dv = below ? sl[0] : (above ? sl[NBINS] : deriv);
        ldacc += __logf(dv);

        yout[(size_t)(rbase + lr) * DIM + ti[t]] = yv;
    }

    // per-row logdet: reduce over the 4 lane-groups (fixed order)
    ldacc += __shfl_xor(ldacc, 16, 64);
    ldacc += __shfl_xor(ldacc, 32, 64);
    if (l < 16) {
        const int row = rbase + lr;
        if (first) logdet[row] = ldacc;
        else       logdet[row] += ldacc;
    }
}

extern "C" void kernel_launch(void* const* d_in, const int* in_sizes, int n_in,
                              void* d_out, int out_size, void* d_ws, size_t ws_size,
                              hipStream_t stream) {
    const float* x  = (const float*)d_in[0];
    const float* W1 = (const float*)d_in[1];
    const float* b1 = (const float*)d_in[2];
    const float* W2 = (const float*)d_in[3];
    const float* b2 = (const float*)d_in[4];
    const float* W3 = (const float*)d_in[5];
    const float* b3 = (const float*)d_in[6];
    const float* W4 = (const float*)d_in[7];
    const float* b4 = (const float*)d_in[8];
    const int*   mi = (const int*)d_in[9];
    const int*   ti = (const int*)d_in[10];

    float* y      = (float*)d_out;
    float* logdet = y + (size_t)BATCH * DIM;

    short* bW1 = (short*)d_ws;
    short* bW2 = bW1 + NLAYERS * N_W1;
    short* bW3 = bW2 + NLAYERS * N_W2;
    short* bW4 = bW3 + NLAYERS * N_W2;
    float* b4q = (float*)(bW4 + (size_t)NLAYERS * N_W4P);

    cvt_weights<<<512, 256, 0, stream>>>(W1, W2, W3, W4, b4, bW1, bW2, bW3, bW4, b4q);

    dim3 grid(BATCH / MBLK), block(NT);
    for (int L = 0; L < NLAYERS; ++L) {
        flow_layer<<<grid, block, 0, stream>>>(
            (L == 0) ? x : y, y, logdet, (L == 0) ? 1 : 0,
            bW1 + (size_t)L * N_W1, b1 + L * HID,
            bW2 + (size_t)L * N_W2, b2 + L * HID,
            bW3 + (size_t)L * N_W2, b3 + L * HID,
            bW4 + (size_t)L * N_W4P, b4q + (size_t)L * SPLIT * 32,
            mi + L * SPLIT, ti + L * SPLIT);
    }
}

// Round 7
// 351.708 us; speedup vs baseline: 1.5693x; 1.0311x over previous
//
#include <hip/hip_runtime.h>
#include <math.h>

#define BATCH   65536
#define DIM     64
#define HID     128
#define SPLIT   32
#define NBINS   8
#define PDIM    25          // 3*NBINS+1
#define NLAYERS 6
#define R_MIN   (-5.0f)
#define R_MAX   (5.0f)
#define MIN_BIN   1.0e-4f
#define MIN_SLOPE 1.0e-4f
#define SOFF      0.54116666f   // log(exp(1-MIN_SLOPE)-1)

#define ROWSW 16      // rows per wave
#define WAVES 4
#define MBLK  64      // rows per block
#define NT    256
#define W4CH  28      // chunks per t-block after dropping pq=7 (params 28..31 unused)

#define N_W1  (HID*SPLIT)      // 4096
#define N_W2  (HID*HID)        // 16384
#define N_W4P (32*32*HID)      // 131072 (8 tb x 8 pq x 4 kt chunks of 512)
#define N_W4  (SPLIT*PDIM*HID) // 102400

typedef __attribute__((ext_vector_type(8))) short bf16x8;
typedef __attribute__((ext_vector_type(4))) float f32x4;

__device__ __forceinline__ short f2bf(float f) {
    unsigned u = __builtin_bit_cast(unsigned, f);
    unsigned r = u + 0x7FFFu + ((u >> 16) & 1u);   // RNE
    return (short)(r >> 16);
}

__device__ __forceinline__ unsigned pk2(float a, float b) {   // 2xf32 -> packed bf16 (RNE)
    unsigned r;
    asm("v_cvt_pk_bf16_f32 %0, %1, %2" : "=v"(r) : "v"(a), "v"(b));
    return r;
}

// async global->LDS, 16B per lane: LDS dest = uniform base + lane*16
__device__ __forceinline__ void gload16(const short* g, short* s) {
    __builtin_amdgcn_global_load_lds(
        (const __attribute__((address_space(1))) void*)g,
        (__attribute__((address_space(3))) void*)s, 16, 0, 0);
}

// act LDS layout: [group g = k>>2][row r][k&3] shorts, group stride 64 shorts.
__device__ __forceinline__ bf16x8 ldfrag(const short* base) {
    short4 lo = *reinterpret_cast<const short4*>(base);
    short4 hi = *reinterpret_cast<const short4*>(base + 64);
    bf16x8 a;
    a[0]=lo.x; a[1]=lo.y; a[2]=lo.z; a[3]=lo.w;
    a[4]=hi.x; a[5]=hi.y; a[6]=hi.z; a[7]=hi.w;
    return a;
}

// ---- weight conversion prologue (same fragment packing as R5) ----
__global__ void cvt_weights(const float* __restrict__ W1, const float* __restrict__ W2,
                            const float* __restrict__ W3, const float* __restrict__ W4,
                            const float* __restrict__ b4,
                            short* __restrict__ o1, short* __restrict__ o2,
                            short* __restrict__ o3, short* __restrict__ o4,
                            float* __restrict__ b4q) {
    const int stride = gridDim.x * blockDim.x;
    const int i0 = blockIdx.x * blockDim.x + threadIdx.x;
    for (int i = i0; i < NLAYERS*N_W1; i += stride) {
        const int L = i >> 12, rem = i & 4095;
        const int nt = rem >> 9, q = rem & 511;
        const int l = q >> 3, e = q & 7;
        o1[i] = f2bf(W1[L*N_W1 + (nt*16 + (l&15))*SPLIT + (l>>4)*8 + e]);
    }
    for (int i = i0; i < NLAYERS*N_W2; i += stride) {
        const int L = i >> 14, rem = i & 16383;
        const int c = rem >> 9, q = rem & 511;
        const int nt = c >> 2, kt = c & 3;
        const int l = q >> 3, e = q & 7;
        const int src = L*N_W2 + (nt*16 + (l&15))*HID + kt*32 + (l>>4)*8 + e;
        o2[i] = f2bf(W2[src]);
        o3[i] = f2bf(W3[src]);
    }
    for (int i = i0; i < NLAYERS*N_W4P; i += stride) {
        const int L = i >> 17, rem = i & (N_W4P - 1);
        const int c = rem >> 9, q = rem & 511;
        const int tb = c >> 5, pq = (c >> 2) & 7, kt = c & 3;
        const int l = q >> 3, e = q & 7;
        const int t = tb*4 + ((l & 15) >> 2);
        const int p = pq*4 + (l & 3);
        o4[i] = (p < PDIM)
              ? f2bf(W4[(size_t)L*N_W4 + (size_t)(t*PDIM + p)*HID + kt*32 + (l>>4)*8 + e])
              : (short)0;
    }
    for (int i = i0; i < NLAYERS*SPLIT*32; i += stride) {
        const int L = i >> 10, rem = i & 1023;
        const int t = rem >> 5, p = rem & 31;
        b4q[i] = (p < PDIM) ? b4[L*SPLIT*PDIM + t*PDIM + p] : 0.0f;
    }
}

// One coupling layer. Weights staged block-wide into LDS (ping-pong 32KB bufs);
// each wave owns 16 rows; acts are wave-private bf16 fragments in LDS.
__global__ __launch_bounds__(NT, 2) void flow_layer(
    const float* xin, float* yout, float* logdet, const int first,
    const short* __restrict__ bW1, const float* __restrict__ b1,
    const short* __restrict__ bW2, const float* __restrict__ b2,
    const short* __restrict__ bW3, const float* __restrict__ b3,
    const short* __restrict__ bW4, const float* __restrict__ b4q,
    const int* __restrict__ mi, const int* __restrict__ ti)
{
    __shared__ short wbuf[2][16384];              // 2 x 32KB weight buffers
    __shared__ short act[WAVES][32 * 64];         // 32 groups x 16 rows x 4 shorts

    const int tid = threadIdx.x;
    const int wv  = tid >> 6;    // wave id
    const int l   = tid & 63;    // lane
    const int lr  = l & 15;      // row / col-in-tile
    const int lg  = l >> 4;      // 0..3
    const int rbase = blockIdx.x * MBLK + wv * ROWSW;

    short* const actw = &act[wv][0];

    // ---- issue async stage: W1 -> wbuf[0][0:4096], W2 -> wbuf[1] ----
    #pragma unroll
    for (int i = 0; i < 2; ++i) {
        const int c = wv * 2 + i;
        gload16(bW1 + c * 512 + l * 8, &wbuf[0][c * 512]);
    }
    #pragma unroll
    for (int i = 0; i < 8; ++i) {
        const int c = wv * 8 + i;
        gload16(bW2 + c * 512 + l * 8, &wbuf[1][c * 512]);
    }

    // ---- gather: xm -> act groups 0..7 (bf16); L0 copy-through ----
    {
        const int kcol = l & 31;
        const int mc = mi[kcol];
        const int r0 = l >> 5;                    // 0 or 1
        #pragma unroll
        for (int it = 0; it < 8; ++it) {
            const int r = r0 + it * 2;
            const float mv = xin[(size_t)(rbase + r) * DIM + mc];
            actw[(kcol >> 2)*64 + r*4 + (kcol & 3)] = f2bf(mv);
            if (first) yout[(size_t)(rbase + r) * DIM + mc] = mv;
        }
    }
    __syncthreads();   // W1,W2 visible (barrier drains vmcnt); acts ready

    // ================= h1 = relu(W1 @ xm^T + b1)  [K=32] =================
    {
        const bf16x8 afr = ldfrag(&actw[(2*lg)*64 + lr*4]);
        f32x4 c[8];
        #pragma unroll
        for (int nt = 0; nt < 8; ++nt) {
            const float4 bv = *reinterpret_cast<const float4*>(b1 + nt*16 + lg*4);
            c[nt] = (f32x4){bv.x, bv.y, bv.z, bv.w};
        }
        #pragma unroll
        for (int nt = 0; nt < 8; ++nt) {
            const bf16x8 wfr = *reinterpret_cast<const bf16x8*>(&wbuf[0][nt*512 + l*8]);
            c[nt] = __builtin_amdgcn_mfma_f32_16x16x32_bf16(wfr, afr, c[nt], 0, 0, 0);
        }
        #pragma unroll
        for (int nt = 0; nt < 8; ++nt) {
            const unsigned u0 = pk2(fmaxf(c[nt][0], 0.0f), fmaxf(c[nt][1], 0.0f));
            const unsigned u1 = pk2(fmaxf(c[nt][2], 0.0f), fmaxf(c[nt][3], 0.0f));
            *reinterpret_cast<uint2*>(&actw[(nt*4 + lg)*64 + lr*4]) = (uint2){u0, u1};
        }
    }
    __syncthreads();   // all waves done reading wbuf[0] (W1)

    // ---- issue stage W3 -> wbuf[0]; overlaps h2 ----
    #pragma unroll
    for (int i = 0; i < 8; ++i) {
        const int c = wv * 8 + i;
        gload16(bW3 + c * 512 + l * 8, &wbuf[0][c * 512]);
    }

    // ================= h2 = relu(W2 @ h1^T + b2)  [K=128, wbuf[1]] =========
    {
        bf16x8 afr[4];
        #pragma unroll
        for (int kt = 0; kt < 4; ++kt)
            afr[kt] = ldfrag(&actw[(kt*8 + 2*lg)*64 + lr*4]);
        f32x4 c[8];
        #pragma unroll
        for (int nt = 0; nt < 8; ++nt) {
            const float4 bv = *reinterpret_cast<const float4*>(b2 + nt*16 + lg*4);
            c[nt] = (f32x4){bv.x, bv.y, bv.z, bv.w};
        }
        #pragma unroll
        for (int kt = 0; kt < 4; ++kt)
            #pragma unroll
            for (int nt = 0; nt < 8; ++nt) {
                const bf16x8 wfr = *reinterpret_cast<const bf16x8*>(&wbuf[1][(nt*4 + kt)*512 + l*8]);
                c[nt] = __builtin_amdgcn_mfma_f32_16x16x32_bf16(wfr, afr[kt], c[nt], 0, 0, 0);
            }
        #pragma unroll
        for (int nt = 0; nt < 8; ++nt) {
            const unsigned u0 = pk2(fmaxf(c[nt][0], 0.0f), fmaxf(c[nt][1], 0.0f));
            const unsigned u1 = pk2(fmaxf(c[nt][2], 0.0f), fmaxf(c[nt][3], 0.0f));
            *reinterpret_cast<uint2*>(&actw[(nt*4 + lg)*64 + lr*4]) = (uint2){u0, u1};
        }
    }
    __syncthreads();   // W3 visible; all waves done reading wbuf[1] (W2)

    // ---- issue stage W4 tile tb=0 -> wbuf[1]; overlaps h3 ----
    #pragma unroll
    for (int i = 0; i < 7; ++i) {
        const int c = wv * 7 + i;
        gload16(bW4 + (size_t)c * 512 + l * 8, &wbuf[1][c * 512]);
    }

    // ================= h3 = relu(W3 @ h2^T + b3)  [K=128, wbuf[0]] =========
    {
        bf16x8 afr[4];
        #pragma unroll
        for (int kt = 0; kt < 4; ++kt)
            afr[kt] = ldfrag(&actw[(kt*8 + 2*lg)*64 + lr*4]);
        f32x4 c[8];
        #pragma unroll
        for (int nt = 0; nt < 8; ++nt) {
            const float4 bv = *reinterpret_cast<const float4*>(b3 + nt*16 + lg*4);
            c[nt] = (f32x4){bv.x, bv.y, bv.z, bv.w};
        }
        #pragma unroll
        for (int kt = 0; kt < 4; ++kt)
            #pragma unroll
            for (int nt = 0; nt < 8; ++nt) {
                const bf16x8 wfr = *reinterpret_cast<const bf16x8*>(&wbuf[0][(nt*4 + kt)*512 + l*8]);
                c[nt] = __builtin_amdgcn_mfma_f32_16x16x32_bf16(wfr, afr[kt], c[nt], 0, 0, 0);
            }
        #pragma unroll
        for (int nt = 0; nt < 8; ++nt) {
            const unsigned u0 = pk2(fmaxf(c[nt][0], 0.0f), fmaxf(c[nt][1], 0.0f));
            const unsigned u1 = pk2(fmaxf(c[nt][2], 0.0f), fmaxf(c[nt][3], 0.0f));
            *reinterpret_cast<uint2*>(&actw[(nt*4 + lg)*64 + lr*4]) = (uint2){u0, u1};
        }
    }

    // h3 act fragments into registers (held across the whole tb loop)
    bf16x8 afr[4];
    #pragma unroll
    for (int kt = 0; kt < 4; ++kt)
        afr[kt] = ldfrag(&actw[(kt*8 + 2*lg)*64 + lr*4]);

    __syncthreads();   // W4 tb0 visible; all waves done reading wbuf[0] (W3)

    // x / ti 2-deep register rotation (no runtime-indexed arrays)
    const float* rowx = xin + (size_t)(rbase + lr) * DIM;
    int   tcur = ti[lg];
    float xcur = rowx[tcur];

    float ldacc = 0.0f;
    #pragma unroll 1
    for (int tb = 0; tb < 8; ++tb) {
        // issue stage of tile tb+1 into the buffer mfma(tb-1) just finished with
        if (tb < 7) {
            short* wbn = &wbuf[tb & 1][0];
            #pragma unroll
            for (int i = 0; i < 7; ++i) {
                const int c = wv * 7 + i;
                gload16(bW4 + (size_t)((tb + 1) * 32 + c) * 512 + l * 8, wbn + c * 512);
            }
        }
        int   tnxt = tcur;
        float xnxt = xcur;
        if (tb < 7) { tnxt = ti[(tb + 1) * 4 + lg]; xnxt = rowx[tnxt]; }

        const int t = tb*4 + lg;           // this lane's t-dim
        const short* wb = &wbuf[(tb + 1) & 1][0];

        f32x4 c[7];
        #pragma unroll
        for (int pq = 0; pq < 7; ++pq) {
            const float4 bv = *reinterpret_cast<const float4*>(b4q + t*32 + pq*4);
            c[pq] = (f32x4){bv.x, bv.y, bv.z, bv.w};
        }
        #pragma unroll
        for (int kt = 0; kt < 4; ++kt)
            #pragma unroll
            for (int pq = 0; pq < 7; ++pq) {
                const bf16x8 wfr = *reinterpret_cast<const bf16x8*>(wb + (pq*4 + kt)*512 + l*8);
                c[pq] = __builtin_amdgcn_mfma_f32_16x16x32_bf16(wfr, afr[kt], c[pq], 0, 0, 0);
            }

        // lane holds the 28 params of (row = lr, t)
        float p[28];
        #pragma unroll
        for (int pq = 0; pq < 7; ++pq)
            #pragma unroll
            for (int j = 0; j < 4; ++j) p[pq*4 + j] = c[pq][j];

        float sl[NBINS + 1];
        #pragma unroll
        for (int i = 0; i < NBINS + 1; ++i) {
            const float z = p[2*NBINS + i] + SOFF;
            const float sp = (z > 15.0f) ? z : __logf(1.0f + __expf(z));
            sl[i] = sp + MIN_SLOPE;
        }
        float wd[NBINS];
        {
            float mx = p[0];
            #pragma unroll
            for (int i = 1; i < NBINS; ++i) mx = fmaxf(mx, p[i]);
            float sum = 0.0f;
            #pragma unroll
            for (int i = 0; i < NBINS; ++i) { wd[i] = __expf(p[i] - mx); sum += wd[i]; }
            const float sc = __fdividef((R_MAX - R_MIN) - NBINS * MIN_BIN, sum);
            #pragma unroll
            for (int i = 0; i < NBINS; ++i) wd[i] = wd[i] * sc + MIN_BIN;
        }
        float hg[NBINS];
        {
            float mx = p[NBINS];
            #pragma unroll
            for (int i = 1; i < NBINS; ++i) mx = fmaxf(mx, p[NBINS + i]);
            float sum = 0.0f;
            #pragma unroll
            for (int i = 0; i < NBINS; ++i) { hg[i] = __expf(p[NBINS + i] - mx); sum += hg[i]; }
            const float sc = __fdividef((R_MAX - R_MIN) - NBINS * MIN_BIN, sum);
            #pragma unroll
            for (int i = 0; i < NBINS; ++i) hg[i] = hg[i] * sc + MIN_BIN;
        }

        const float x = xcur;

        int b = 0;
        {
            float cx = R_MIN;
            #pragma unroll
            for (int i = 1; i < NBINS; ++i) { cx += wd[i-1]; b += (cx <= x) ? 1 : 0; }
        }
        float x_k = R_MIN, y_k = R_MIN, wsel = wd[0], hsel = hg[0], d_k = sl[0], d_k1 = sl[1];
        {
            float cx = R_MIN, cy = R_MIN;
            #pragma unroll
            for (int i = 0; i < NBINS; ++i) {
                if (i == b) { x_k = cx; y_k = cy; wsel = wd[i]; hsel = hg[i];
                              d_k = sl[i]; d_k1 = sl[i+1]; }
                cx += wd[i]; cy += hg[i];
            }
        }

        const float invw = __fdividef(1.0f, wsel);
        float xi = (x - x_k) * invw;
        xi = fminf(fmaxf(xi, 0.0f), 1.0f);
        const float s    = hsel * invw;
        const float xi1m = 1.0f - xi;
        const float q    = xi * xi1m;
        const float num  = s * xi * xi + d_k * q;
        const float den  = s + (d_k1 + d_k - 2.0f * s) * q;
        const float invden = __fdividef(1.0f, den);
        const float y_sp = y_k + hsel * num * invden;
        const float deriv = s * s * (d_k1 * xi * xi + 2.0f * s * q + d_k * xi1m * xi1m)
                            * invden * invden;

        const bool below = x < R_MIN;
        const bool above = x > R_MAX;
        const float yv = below ? ((x - R_MIN) * sl[0]     + R_MIN)
                       : (above ? ((x - R_MAX) * sl[NBINS] + R_MAX) : y_sp);
        const float dv = below ? sl[0] : (above ? sl[NBINS] : deriv);
        ldacc += __logf(dv);

        yout[(size_t)(rbase + lr) * DIM + tcur] = yv;

        __syncthreads();   // drain stage(tb+1); all waves done reading wb
        tcur = tnxt; xcur = xnxt;
    }

    // per-row logdet: reduce over the 4 lane-groups (fixed order)
    ldacc += __shfl_xor(ldacc, 16, 64);
    ldacc += __shfl_xor(ldacc, 32, 64);
    if (l < 16) {
        const int row = rbase + lr;
        if (first) logdet[row] = ldacc;
        else       logdet[row] += ldacc;
    }
}

extern "C" void kernel_launch(void* const* d_in, const int* in_sizes, int n_in,
                              void* d_out, int out_size, void* d_ws, size_t ws_size,
                              hipStream_t stream) {
    const float* x  = (const float*)d_in[0];
    const float* W1 = (const float*)d_in[1];
    const float* b1 = (const float*)d_in[2];
    const float* W2 = (const float*)d_in[3];
    const float* b2 = (const float*)d_in[4];
    const float* W3 = (const float*)d_in[5];
    const float* b3 = (const float*)d_in[6];
    const float* W4 = (const float*)d_in[7];
    const float* b4 = (const float*)d_in[8];
    const int*   mi = (const int*)d_in[9];
    const int*   ti = (const int*)d_in[10];

    float* y      = (float*)d_out;
    float* logdet = y + (size_t)BATCH * DIM;

    short* bW1 = (short*)d_ws;
    short* bW2 = bW1 + NLAYERS * N_W1;
    short* bW3 = bW2 + NLAYERS * N_W2;
    short* bW4 = bW3 + NLAYERS * N_W2;
    float* b4q = (float*)(bW4 + (size_t)NLAYERS * N_W4P);

    cvt_weights<<<512, 256, 0, stream>>>(W1, W2, W3, W4, b4, bW1, bW2, bW3, bW4, b4q);

    dim3 grid(BATCH / MBLK), block(NT);
    for (int L = 0; L < NLAYERS; ++L) {
        flow_layer<<<grid, block, 0, stream>>>(
            (L == 0) ? x : y, y, logdet, (L == 0) ? 1 : 0,
            bW1 + (size_t)L * N_W1, b1 + L * HID,
            bW2 + (size_t)L * N_W2, b2 + L * HID,
            bW3 + (size_t)L * N_W2, b3 + L * HID,
            bW4 + (size_t)L * N_W4P, b4q + (size_t)L * SPLIT * 32,
            mi + L * SPLIT, ti + L * SPLIT);
    }
}

// Round 8
// 349.566 us; speedup vs baseline: 1.5789x; 1.0061x over previous
//
#include <hip/hip_runtime.h>
#include <math.h>

#define BATCH   65536
#define DIM     64
#define HID     128
#define SPLIT   32
#define NBINS   8
#define PDIM    25          // 3*NBINS+1
#define NLAYERS 6
#define R_MIN   (-5.0f)
#define R_MAX   (5.0f)
#define MIN_BIN   1.0e-4f
#define MIN_SLOPE 1.0e-4f
#define SOFF      0.54116666f   // log(exp(1-MIN_SLOPE)-1)

#define ROWSW 16      // rows per wave
#define WAVES 4
#define MBLK  64      // rows per block
#define NT    256

#define N_W1  (HID*SPLIT)      // 4096
#define N_W2  (HID*HID)        // 16384
#define N_W4P (32*32*HID)      // 131072 (8 tb x 8 pq x 4 kt chunks of 512)
#define N_W4  (SPLIT*PDIM*HID) // 102400

typedef __attribute__((ext_vector_type(8))) short bf16x8;
typedef __attribute__((ext_vector_type(4))) float f32x4;

__device__ __forceinline__ short f2bf(float f) {
    unsigned u = __builtin_bit_cast(unsigned, f);
    unsigned r = u + 0x7FFFu + ((u >> 16) & 1u);   // RNE
    return (short)(r >> 16);
}

__device__ __forceinline__ unsigned pk2(float a, float b) {   // 2xf32 -> packed bf16 (RNE)
    unsigned r;
    asm("v_cvt_pk_bf16_f32 %0, %1, %2" : "=v"(r) : "v"(a), "v"(b));
    return r;
}

// act LDS layout: [group g = k>>2][row r][k&3] shorts, group stride 64 shorts.
__device__ __forceinline__ bf16x8 ldfrag(const short* base) {
    short4 lo = *reinterpret_cast<const short4*>(base);
    short4 hi = *reinterpret_cast<const short4*>(base + 64);
    bf16x8 a;
    a[0]=lo.x; a[1]=lo.y; a[2]=lo.z; a[3]=lo.w;
    a[4]=hi.x; a[5]=hi.y; a[6]=hi.z; a[7]=hi.w;
    return a;
}

// ---- weight conversion prologue (fragment packing, same as R5/R6) ----
__global__ void cvt_weights(const float* __restrict__ W1, const float* __restrict__ W2,
                            const float* __restrict__ W3, const float* __restrict__ W4,
                            const float* __restrict__ b4,
                            short* __restrict__ o1, short* __restrict__ o2,
                            short* __restrict__ o3, short* __restrict__ o4,
                            float* __restrict__ b4q) {
    const int stride = gridDim.x * blockDim.x;
    const int i0 = blockIdx.x * blockDim.x + threadIdx.x;
    for (int i = i0; i < NLAYERS*N_W1; i += stride) {
        const int L = i >> 12, rem = i & 4095;
        const int nt = rem >> 9, q = rem & 511;
        const int l = q >> 3, e = q & 7;
        o1[i] = f2bf(W1[L*N_W1 + (nt*16 + (l&15))*SPLIT + (l>>4)*8 + e]);
    }
    for (int i = i0; i < NLAYERS*N_W2; i += stride) {
        const int L = i >> 14, rem = i & 16383;
        const int c = rem >> 9, q = rem & 511;
        const int nt = c >> 2, kt = c & 3;
        const int l = q >> 3, e = q & 7;
        const int src = L*N_W2 + (nt*16 + (l&15))*HID + kt*32 + (l>>4)*8 + e;
        o2[i] = f2bf(W2[src]);
        o3[i] = f2bf(W3[src]);
    }
    for (int i = i0; i < NLAYERS*N_W4P; i += stride) {
        const int L = i >> 17, rem = i & (N_W4P - 1);
        const int c = rem >> 9, q = rem & 511;
        const int tb = c >> 5, pq = (c >> 2) & 7, kt = c & 3;
        const int l = q >> 3, e = q & 7;
        const int t = tb*4 + ((l & 15) >> 2);
        const int p = pq*4 + (l & 3);
        o4[i] = (p < PDIM)
              ? f2bf(W4[(size_t)L*N_W4 + (size_t)(t*PDIM + p)*HID + kt*32 + (l>>4)*8 + e])
              : (short)0;
    }
    for (int i = i0; i < NLAYERS*SPLIT*32; i += stride) {
        const int L = i >> 10, rem = i & 1023;
        const int t = rem >> 5, p = rem & 31;
        b4q[i] = (p < PDIM) ? b4[L*SPLIT*PDIM + t*PDIM + p] : 0.0f;
    }
}

// One coupling layer (R5 structure: direct-L2 weights, wave-private, no barriers).
// UNR = how many independent tb (spline) iterations are put in flight per step:
// A/B probe for the latency-bound theory.
template<int UNR>
__global__ __launch_bounds__(NT, 4) void flow_layer(
    const float* xin, float* yout, float* logdet, const int first,
    const short* __restrict__ bW1, const float* __restrict__ b1,
    const short* __restrict__ bW2, const float* __restrict__ b2,
    const short* __restrict__ bW3, const float* __restrict__ b3,
    const short* __restrict__ bW4, const float* __restrict__ b4q,
    const int* __restrict__ mi, const int* __restrict__ ti)
{
    __shared__ short act[WAVES][32 * 64];         // 32 groups x 16 rows x 4 shorts
    __shared__ float xts[WAVES][ROWSW][33];       // spline inputs (f32)

    const int tid = threadIdx.x;
    const int wv  = tid >> 6;    // wave id
    const int l   = tid & 63;    // lane
    const int lr  = l & 15;      // row / col-in-tile
    const int lg  = l >> 4;      // 0..3
    const int rbase = blockIdx.x * MBLK + wv * ROWSW;

    short* const actw = &act[wv][0];

    // ---- gather: xm -> act groups 0..7 (bf16), xt -> xts (f32) ----
    {
        const int kcol = l & 31;
        const int mc = mi[kcol], tc = ti[kcol];
        const int r0 = l >> 5;                    // 0 or 1
        #pragma unroll
        for (int it = 0; it < 8; ++it) {
            const int r = r0 + it * 2;
            const float* row = xin + (size_t)(rbase + r) * DIM;
            const float mv = row[mc];
            actw[(kcol >> 2)*64 + r*4 + (kcol & 3)] = f2bf(mv);
            xts[wv][r][kcol] = row[tc];
            if (first) yout[(size_t)(rbase + r) * DIM + mc] = mv;  // copy-through (L0)
        }
    }

    // ================= h1 = relu(W1 @ xm^T + b1)  [K=32] =================
    {
        const bf16x8 afr = ldfrag(&actw[(2*lg)*64 + lr*4]);
        f32x4 c[8];
        #pragma unroll
        for (int nt = 0; nt < 8; ++nt) {
            const float4 bv = *reinterpret_cast<const float4*>(b1 + nt*16 + lg*4);
            c[nt] = (f32x4){bv.x, bv.y, bv.z, bv.w};
        }
        #pragma unroll
        for (int nt = 0; nt < 8; ++nt) {
            const bf16x8 wfr = *reinterpret_cast<const bf16x8*>(bW1 + (size_t)nt*512 + l*8);
            c[nt] = __builtin_amdgcn_mfma_f32_16x16x32_bf16(wfr, afr, c[nt], 0, 0, 0);
        }
        #pragma unroll
        for (int nt = 0; nt < 8; ++nt) {
            const unsigned u0 = pk2(fmaxf(c[nt][0], 0.0f), fmaxf(c[nt][1], 0.0f));
            const unsigned u1 = pk2(fmaxf(c[nt][2], 0.0f), fmaxf(c[nt][3], 0.0f));
            *reinterpret_cast<uint2*>(&actw[(nt*4 + lg)*64 + lr*4]) = (uint2){u0, u1};
        }
    }

    // ================= h2 / h3  [K=128] =================
    #pragma unroll 1
    for (int ph = 0; ph < 2; ++ph) {
        const short* Wp = ph ? bW3 : bW2;
        const float* bp = ph ? b3  : b2;
        bf16x8 afr[4];
        #pragma unroll
        for (int kt = 0; kt < 4; ++kt)
            afr[kt] = ldfrag(&actw[(kt*8 + 2*lg)*64 + lr*4]);
        f32x4 c[8];
        #pragma unroll
        for (int nt = 0; nt < 8; ++nt) {
            const float4 bv = *reinterpret_cast<const float4*>(bp + nt*16 + lg*4);
            c[nt] = (f32x4){bv.x, bv.y, bv.z, bv.w};
        }
        #pragma unroll
        for (int kt = 0; kt < 4; ++kt)
            #pragma unroll
            for (int nt = 0; nt < 8; ++nt) {
                const bf16x8 wfr = *reinterpret_cast<const bf16x8*>(Wp + (size_t)(nt*4 + kt)*512 + l*8);
                c[nt] = __builtin_amdgcn_mfma_f32_16x16x32_bf16(wfr, afr[kt], c[nt], 0, 0, 0);
            }
        #pragma unroll
        for (int nt = 0; nt < 8; ++nt) {
            const unsigned u0 = pk2(fmaxf(c[nt][0], 0.0f), fmaxf(c[nt][1], 0.0f));
            const unsigned u1 = pk2(fmaxf(c[nt][2], 0.0f), fmaxf(c[nt][3], 0.0f));
            *reinterpret_cast<uint2*>(&actw[(nt*4 + lg)*64 + lr*4]) = (uint2){u0, u1};
        }
    }

    // ================= W4 params + RQS spline =================
    bf16x8 afr[4];
    #pragma unroll
    for (int kt = 0; kt < 4; ++kt)
        afr[kt] = ldfrag(&actw[(kt*8 + 2*lg)*64 + lr*4]);

    float ldacc = 0.0f;

    auto body = [&](const int tb) {
        const int t = tb*4 + lg;           // this lane's t-dim
        f32x4 c[7];
        #pragma unroll
        for (int pq = 0; pq < 7; ++pq) {
            const float4 bv = *reinterpret_cast<const float4*>(b4q + t*32 + pq*4);
            c[pq] = (f32x4){bv.x, bv.y, bv.z, bv.w};
        }
        #pragma unroll
        for (int kt = 0; kt < 4; ++kt)
            #pragma unroll
            for (int pq = 0; pq < 7; ++pq) {
                const bf16x8 wfr = *reinterpret_cast<const bf16x8*>(
                    bW4 + (size_t)((tb*8 + pq)*4 + kt)*512 + l*8);
                c[pq] = __builtin_amdgcn_mfma_f32_16x16x32_bf16(wfr, afr[kt], c[pq], 0, 0, 0);
            }

        // lane holds the 28 params of (row = lr, t):  P(i) = c[i>>2][i&3]
#define P(i) c[(i)>>2][(i)&3]
        // softmax WITHOUT max-subtraction (params are O(1); mathematically identical)
        float wd[NBINS], hg[NBINS];
        float sw = 0.0f, sh = 0.0f;
        #pragma unroll
        for (int i = 0; i < NBINS; ++i) { wd[i] = __expf(P(i));         sw += wd[i]; }
        #pragma unroll
        for (int i = 0; i < NBINS; ++i) { hg[i] = __expf(P(NBINS + i)); sh += hg[i]; }
        const float scw = __fdividef((R_MAX - R_MIN) - NBINS * MIN_BIN, sw);
        const float sch = __fdividef((R_MAX - R_MIN) - NBINS * MIN_BIN, sh);
        #pragma unroll
        for (int i = 0; i < NBINS; ++i) { wd[i] = wd[i]*scw + MIN_BIN; hg[i] = hg[i]*sch + MIN_BIN; }

        const float x = xts[wv][lr][t];

        // merged cumsum + bin select (last knot with x_pos <= x wins)
        float cx = R_MIN, cy = R_MIN;
        float x_k = R_MIN, y_k = R_MIN, wsel = wd[0], hsel = hg[0];
        float z0 = P(16), z1 = P(17);
        #pragma unroll
        for (int i = 1; i < NBINS; ++i) {
            cx += wd[i-1]; cy += hg[i-1];
            const bool tk = (cx <= x);
            x_k  = tk ? cx        : x_k;
            y_k  = tk ? cy        : y_k;
            wsel = tk ? wd[i]     : wsel;
            hsel = tk ? hg[i]     : hsel;
            z0   = tk ? P(16 + i) : z0;
            z1   = tk ? P(17 + i) : z1;
        }

        // softplus only on the 4 slopes actually needed
        auto sp = [](float v) {
            const float z = v + SOFF;
            return ((z > 15.0f) ? z : __logf(1.0f + __expf(z))) + MIN_SLOPE;
        };
        const float d_k = sp(z0), d_k1 = sp(z1);
        const float sl0 = sp(P(16)), sl8 = sp(P(24));
#undef P

        const float invw = __fdividef(1.0f, wsel);
        float xi = (x - x_k) * invw;
        xi = fminf(fmaxf(xi, 0.0f), 1.0f);
        const float s    = hsel * invw;
        const float xi1m = 1.0f - xi;
        const float q    = xi * xi1m;
        const float num  = s * xi * xi + d_k * q;
        const float den  = s + (d_k1 + d_k - 2.0f * s) * q;
        const float invden = __fdividef(1.0f, den);
        const float y_sp = y_k + hsel * num * invden;
        const float deriv = s * s * (d_k1 * xi * xi + 2.0f * s * q + d_k * xi1m * xi1m)
                            * invden * invden;

        const bool below = x < R_MIN;
        const bool above = x > R_MAX;
        const float yv = below ? ((x - R_MIN) * sl0 + R_MIN)
                       : (above ? ((x - R_MAX) * sl8 + R_MAX) : y_sp);
        const float dv = below ? sl0 : (above ? sl8 : deriv);
        ldacc += __logf(dv);

        yout[(size_t)(rbase + lr) * DIM + ti[t]] = yv;
    };

    if constexpr (UNR == 1) {
        #pragma unroll 1
        for (int tb = 0; tb < 8; ++tb) body(tb);
    } else {
        #pragma unroll 1
        for (int tb = 0; tb < 8; tb += 2) { body(tb); body(tb + 1); }
    }

    // per-row logdet: reduce over the 4 lane-groups (fixed order)
    ldacc += __shfl_xor(ldacc, 16, 64);
    ldacc += __shfl_xor(ldacc, 32, 64);
    if (l < 16) {
        const int row = rbase + lr;
        if (first) logdet[row] = ldacc;
        else       logdet[row] += ldacc;
    }
}

extern "C" void kernel_launch(void* const* d_in, const int* in_sizes, int n_in,
                              void* d_out, int out_size, void* d_ws, size_t ws_size,
                              hipStream_t stream) {
    const float* x  = (const float*)d_in[0];
    const float* W1 = (const float*)d_in[1];
    const float* b1 = (const float*)d_in[2];
    const float* W2 = (const float*)d_in[3];
    const float* b2 = (const float*)d_in[4];
    const float* W3 = (const float*)d_in[5];
    const float* b3 = (const float*)d_in[6];
    const float* W4 = (const float*)d_in[7];
    const float* b4 = (const float*)d_in[8];
    const int*   mi = (const int*)d_in[9];
    const int*   ti = (const int*)d_in[10];

    float* y      = (float*)d_out;
    float* logdet = y + (size_t)BATCH * DIM;

    short* bW1 = (short*)d_ws;
    short* bW2 = bW1 + NLAYERS * N_W1;
    short* bW3 = bW2 + NLAYERS * N_W2;
    short* bW4 = bW3 + NLAYERS * N_W2;
    float* b4q = (float*)(bW4 + (size_t)NLAYERS * N_W4P);

    cvt_weights<<<512, 256, 0, stream>>>(W1, W2, W3, W4, b4, bW1, bW2, bW3, bW4, b4q);

    dim3 grid(BATCH / MBLK), block(NT);
    for (int L = 0; L < NLAYERS; ++L) {
        const float* in = (L == 0) ? x : y;
        const int first = (L == 0) ? 1 : 0;
        const short* w1 = bW1 + (size_t)L * N_W1;
        const short* w2 = bW2 + (size_t)L * N_W2;
        const short* w3 = bW3 + (size_t)L * N_W2;
        const short* w4 = bW4 + (size_t)L * N_W4P;
        const float* bb1 = b1 + L * HID, *bb2 = b2 + L * HID, *bb3 = b3 + L * HID;
        const float* bq = b4q + (size_t)L * SPLIT * 32;
        const int* mil = mi + L * SPLIT, *til = ti + L * SPLIT;
        // A/B: layers {0,1,4} -> UNR=1, layers {2,3,5} -> UNR=2 (parity-balanced)
        if (L == 0 || L == 1 || L == 4)
            flow_layer<1><<<grid, block, 0, stream>>>(in, y, logdet, first,
                w1, bb1, w2, bb2, w3, bb3, w4, bq, mil, til);
        else
            flow_layer<2><<<grid, block, 0, stream>>>(in, y, logdet, first,
                w1, bb1, w2, bb2, w3, bb3, w4, bq, mil, til);
    }
}